// Round 8
// baseline (1198.539 us; speedup 1.0000x reference)
//
#include <hip/hip_runtime.h>
#include <stdint.h>

// ============================================================================
// LSTM stack, batch-sliced: reference returns out[:, -1] == batch element 255
// only -> single sequence (T=512) through 4 layers (H=256) + final linear.
//
// Round 8 = round 7 + three additive fixes:
//   (1) delayed h-store (NO startup slack this time): scan stores h(t-1) at
//       the TOP of step t, ~4000cy before the barrier that vmcnt(0)-drains it
//       -> store-ack-to-coherence-point exposure removed. Publishes value t
//       ("h(0..t-1) visible"); epilogue stores h(511), publishes 512.
//   (2) weight f32->fp16 packing fused into each pipeline WG's weight load
//       (removes pack_all dispatch + wpk memory round-trip).
//   (3) final_fn stages h via uint2 ds_write_b64 (conflict-free; round-7's
//       stride-2 scalar writes were the 524288 SQ_LDS_BANK_CONFLICT).
//   Scan dot block / proj body / wait structure byte-identical to round 7.
// ============================================================================

typedef _Float16 half2v __attribute__((ext_vector_type(2)));

__device__ __forceinline__ float fdot2u(uint32_t w, uint32_t h, float acc) {
#if __has_builtin(__builtin_amdgcn_fdot2)
  return __builtin_amdgcn_fdot2(__builtin_bit_cast(half2v, w),
                                __builtin_bit_cast(half2v, h), acc, false);
#else
  half2v wv = __builtin_bit_cast(half2v, w);
  half2v hv = __builtin_bit_cast(half2v, h);
  acc += (float)wv[0] * (float)hv[0];
  acc += (float)wv[1] * (float)hv[1];
  return acc;
#endif
}

__device__ __forceinline__ uint32_t pk2(float a, float b) {
  union { _Float16 h; uint16_t u; } x, y;
  x.h = (_Float16)a;
  y.h = (_Float16)b;
  return (uint32_t)x.u | ((uint32_t)y.u << 16);
}

__device__ __forceinline__ float sigmoidf_(float x) {
  return 1.f / (1.f + __expf(-x));
}
__device__ __forceinline__ float tanhf_(float x) {
  return 1.f - 2.f / (__expf(2.f * x) + 1.f);  // exp overflow -> returns 1
}

#define CNT_STRIDE 32  // ints per counter slot = 128 B = 1 cacheline

__device__ __forceinline__ int cnt_load(const int* p) {
  return __hip_atomic_load(p, __ATOMIC_RELAXED, __HIP_MEMORY_SCOPE_AGENT);
}
__device__ __forceinline__ void cnt_store(int* p, int v) {
  __hip_atomic_store(p, v, __ATOMIC_RELAXED, __HIP_MEMORY_SCOPE_AGENT);
}
// device-coherent (sc0 sc1) data accesses -- no cache maintenance
__device__ __forceinline__ float ldg_f32(const float* p) {
  uint32_t u = __hip_atomic_load((const uint32_t*)p, __ATOMIC_RELAXED,
                                 __HIP_MEMORY_SCOPE_AGENT);
  return __builtin_bit_cast(float, u);
}
__device__ __forceinline__ void stg_f32(float* p, float v) {
  __hip_atomic_store((uint32_t*)p, __builtin_bit_cast(uint32_t, v),
                     __ATOMIC_RELAXED, __HIP_MEMORY_SCOPE_AGENT);
}
__device__ __forceinline__ uint64_t ldg_u64(const float* p) {
  return __hip_atomic_load((const uint64_t*)p, __ATOMIC_RELAXED,
                           __HIP_MEMORY_SCOPE_AGENT);
}

// spin until *p >= need; rdy caches the last observed value (monotone counter)
__device__ __forceinline__ void wait_ge(const int* p, int need, int& rdy) {
  while (rdy < need) {
    rdy = cnt_load(p);
    if (rdy < need) __builtin_amdgcn_s_sleep(2);
  }
  asm volatile("" ::: "memory");  // keep data loads below the poll (compiler)
}

__global__ void zero_cnt(int* c) {
  if (threadIdx.x < 16 * CNT_STRIDE) c[threadIdx.x] = 0;
}

// ---- layer-0 input projection (from x, fully parallel, f32)
__global__ __launch_bounds__(256) void proj_gemm(const float* __restrict__ in, int istride, int K,
                                                 const float* __restrict__ W,
                                                 const float* __restrict__ bih,
                                                 const float* __restrict__ bhh,
                                                 float* __restrict__ xg) {
  __shared__ float xs[8][512];
  const int tid = threadIdx.x;
  const int r = blockIdx.x * 256 + tid;
  const int t0 = blockIdx.y * 8;
  for (int tt = 0; tt < 8; ++tt)
    for (int k = tid; k < K; k += 256)
      xs[tt][k] = in[(size_t)(t0 + tt) * istride + k];
  __syncthreads();
  float bias = bih[r] + bhh[r];
  float acc[8];
#pragma unroll
  for (int j = 0; j < 8; ++j) acc[j] = bias;
  const float* wr = W + (size_t)r * K;
  for (int k = 0; k < K; k += 4) {
    float4 w4 = *reinterpret_cast<const float4*>(wr + k);
#pragma unroll
    for (int j = 0; j < 8; ++j)
      acc[j] += xs[j][k] * w4.x + xs[j][k + 1] * w4.y + xs[j][k + 2] * w4.z +
                xs[j][k + 3] * w4.w;
  }
#pragma unroll
  for (int j = 0; j < 8; ++j) xg[(size_t)(t0 + j) * 1024 + r] = acc[j];
}

// ============================ pipeline stages ===============================

// scan: 512 thr; thread 2j: rows (j, j+256); thread 2j+1: rows (j+512, j+768).
// Self-packs whh f32 -> fp16 pairs at load. Delayed h-store (h(t-1) at top of
// step t). Counter semantics: cnt[l] == v  <=>  h(0..v-1) stored & visible.
__device__ void scan_fn(int l, const float* __restrict__ whh,
                        const float* __restrict__ xgsrc,
                        float* __restrict__ hseq, int* __restrict__ cnt) {
  __shared__ __align__(16) uint4 wlds[8 * 2 * 512];   // 128 KB
  __shared__ __align__(16) uint16_t hbuf[2][256];
  const int tid = threadIdx.x;
  const int j = tid >> 1;
  const int odd = tid & 1;
  const int rA = j + (odd ? 512 : 0);
  const int rB = rA + 256;

  uint32_t wA[96], wB[96];
  {
    const float4* gA = reinterpret_cast<const float4*>(whh + (size_t)rA * 256);
    const float4* gB = reinterpret_cast<const float4*>(whh + (size_t)rB * 256);
#pragma unroll
    for (int q = 0; q < 24; ++q) {
      float4 a0 = gA[2 * q], a1 = gA[2 * q + 1];
      wA[4 * q + 0] = pk2(a0.x, a0.y); wA[4 * q + 1] = pk2(a0.z, a0.w);
      wA[4 * q + 2] = pk2(a1.x, a1.y); wA[4 * q + 3] = pk2(a1.z, a1.w);
      float4 b0 = gB[2 * q], b1 = gB[2 * q + 1];
      wB[4 * q + 0] = pk2(b0.x, b0.y); wB[4 * q + 1] = pk2(b0.z, b0.w);
      wB[4 * q + 2] = pk2(b1.x, b1.y); wB[4 * q + 3] = pk2(b1.z, b1.w);
    }
#pragma unroll
    for (int c = 0; c < 8; ++c) {
      float4 t0 = gA[48 + 2 * c], t1 = gA[49 + 2 * c];
      uint4 v;
      v.x = pk2(t0.x, t0.y); v.y = pk2(t0.z, t0.w);
      v.z = pk2(t1.x, t1.y); v.w = pk2(t1.z, t1.w);
      wlds[(c * 2 + 0) * 512 + tid] = v;
      float4 u0 = gB[48 + 2 * c], u1 = gB[49 + 2 * c];
      uint4 w;
      w.x = pk2(u0.x, u0.y); w.y = pk2(u0.z, u0.w);
      w.z = pk2(u1.x, u1.y); w.w = pk2(u1.z, u1.w);
      wlds[(c * 2 + 1) * 512 + tid] = w;
    }
  }
  if (tid < 256) hbuf[0][tid] = 0;
  __syncthreads();

  const int* mycnt = &cnt[(4 + (l - 1) * 2 + odd) * CNT_STRIDE];
  int rdy = 0;
  if (l) wait_ge(mycnt, 1, rdy);
  float c_ = 0.f;
  float xga = ldg_f32(xgsrc + rA), xgb = ldg_f32(xgsrc + rB);
  float hprev = 0.f;  // h(t-1), stored one step late (even threads)
  int pp = 0;
  for (int t = 0; t < 512; ++t) {
    const int tn = (t < 511) ? (t + 1) : 511;
    if (l) {
      int need = (t + 2 > 512) ? 512 : (t + 2);
      wait_ge(mycnt, need, rdy);
    }
    // delayed h-store: a full dot block ahead of this step's barrier drain
    if (!odd && t > 0) stg_f32(hseq + (t - 1) * 256 + j, hprev);
    float nxa = ldg_f32(xgsrc + tn * 1024 + rA);  // prefetch t+1
    float nxb = ldg_f32(xgsrc + tn * 1024 + rB);

    float accA0 = xga, accA1 = 0.f, accB0 = xgb, accB1 = 0.f;
    const uint4* hv4 = reinterpret_cast<const uint4*>(&hbuf[pp][0]);
#pragma unroll
    for (int ch = 0; ch < 24; ++ch) {
      uint4 h4 = hv4[ch];
      accA0 = fdot2u(wA[4 * ch + 0], h4.x, accA0);
      accA1 = fdot2u(wA[4 * ch + 1], h4.y, accA1);
      accA0 = fdot2u(wA[4 * ch + 2], h4.z, accA0);
      accA1 = fdot2u(wA[4 * ch + 3], h4.w, accA1);
      accB0 = fdot2u(wB[4 * ch + 0], h4.x, accB0);
      accB1 = fdot2u(wB[4 * ch + 1], h4.y, accB1);
      accB0 = fdot2u(wB[4 * ch + 2], h4.z, accB0);
      accB1 = fdot2u(wB[4 * ch + 3], h4.w, accB1);
    }
#pragma unroll
    for (int cc = 0; cc < 8; ++cc) {
      uint4 h4 = hv4[24 + cc];
      uint4 wa = wlds[(cc * 2 + 0) * 512 + tid];
      uint4 wb = wlds[(cc * 2 + 1) * 512 + tid];
      accA0 = fdot2u(wa.x, h4.x, accA0);
      accA1 = fdot2u(wa.y, h4.y, accA1);
      accA0 = fdot2u(wa.z, h4.z, accA0);
      accA1 = fdot2u(wa.w, h4.w, accA1);
      accB0 = fdot2u(wb.x, h4.x, accB0);
      accB1 = fdot2u(wb.y, h4.y, accB1);
      accB0 = fdot2u(wb.z, h4.z, accB0);
      accB1 = fdot2u(wb.w, h4.w, accB1);
    }
    float accA = accA0 + accA1;
    float accB = accB0 + accB1;

    float o0 = __shfl_xor(accA, 1);
    float o1 = __shfl_xor(accB, 1);
    float pi = odd ? o0 : accA;
    float pf = odd ? o1 : accB;
    float pg = odd ? accA : o0;
    float po = odd ? accB : o1;

    c_ = sigmoidf_(pf) * c_ + sigmoidf_(pi) * tanhf_(pg);
    float h = sigmoidf_(po) * tanhf_(c_);
    if (!odd) {
      union { _Float16 hf; uint16_t u; } cv;
      cv.hf = (_Float16)h;
      hbuf[pp ^ 1][j] = cv.u;
    }
    hprev = h;
    __syncthreads();  // drains old stores (already acked) + hbuf visible
    if (tid == 0) cnt_store(&cnt[l * CNT_STRIDE], t);  // h(0..t-1) ready
    pp ^= 1;
    xga = nxa;
    xgb = nxb;
  }
  // epilogue: final h(511) store, drain, publish 512
  if (!odd) stg_f32(hseq + 511 * 256 + j, hprev);
  __syncthreads();
  if (tid == 0) cnt_store(&cnt[l * CNT_STRIDE], 512);
}

// proj: 512 thr, WG owns rows [half*512, half*512+512), 1 row/thread.
// Self-packs wih f32 -> fp16 pairs. 4-step chunks (round-7 proven).
__device__ void proj_fn(int l, int half, const float* __restrict__ wih,
                        const float* __restrict__ bih, const float* __restrict__ bhh,
                        const float* __restrict__ hsrc,   // hseq layer l-1 (f32)
                        float* __restrict__ xgdst, int* __restrict__ cnt) {
  __shared__ __align__(16) uint32_t hpk[4][128];  // 4 steps of packed fp16 h
  const int tid = threadIdx.x;
  const int row = half * 512 + tid;

  uint32_t wr_[128];
  {
    const float4* g = reinterpret_cast<const float4*>(wih + (size_t)row * 256);
#pragma unroll
    for (int q = 0; q < 32; ++q) {
      float4 f0 = g[2 * q], f1 = g[2 * q + 1];
      wr_[4 * q + 0] = pk2(f0.x, f0.y); wr_[4 * q + 1] = pk2(f0.z, f0.w);
      wr_[4 * q + 2] = pk2(f1.x, f1.y); wr_[4 * q + 3] = pk2(f1.z, f1.w);
    }
  }
  const float bias = bih[row] + bhh[row];
  const int* prev = &cnt[(l - 1) * CNT_STRIDE];
  int* mine = &cnt[(4 + (l - 1) * 2 + half) * CNT_STRIDE];
  int rdy = 0;
  const int s4 = tid >> 7;    // pack slot 0..3 (step within chunk)
  const int c4 = tid & 127;   // column pair

  for (int tt = 0; tt < 128; ++tt) {
    const int t0 = tt * 4;
    wait_ge(prev, t0 + 4, rdy);  // h(t0..t0+3) visible
    {
      uint64_t hv = ldg_u64(hsrc + (t0 + s4) * 256 + 2 * c4);  // one RTT, batched
      float hx = __builtin_bit_cast(float, (uint32_t)hv);
      float hy = __builtin_bit_cast(float, (uint32_t)(hv >> 32));
      hpk[s4][c4] = pk2(hx, hy);
    }
    __syncthreads();  // 4 steps of h staged
#pragma unroll
    for (int s = 0; s < 4; ++s) {
      float a0 = bias, a1 = 0.f;
      const uint4* hv4 = reinterpret_cast<const uint4*>(hpk[s]);
#pragma unroll
      for (int q = 0; q < 32; ++q) {
        uint4 h4 = hv4[q];
        a0 = fdot2u(wr_[4 * q + 0], h4.x, a0);
        a1 = fdot2u(wr_[4 * q + 1], h4.y, a1);
        a0 = fdot2u(wr_[4 * q + 2], h4.z, a0);
        a1 = fdot2u(wr_[4 * q + 3], h4.w, a1);
      }
      stg_f32(xgdst + (t0 + s) * 1024 + row, a0 + a1);
    }
    __syncthreads();  // all 4 xg stores drained; hpk reads done
    if (tid == 0) cnt_store(mine, t0 + 4);  // xg(0..t0+3) ready
  }
}

// final linear, fused: streams cnt[3]. 2 threads/row, f32 weights in regs.
__device__ void final_fn(const float* __restrict__ lrw, const float* __restrict__ lrb,
                         const float* __restrict__ h3, float* __restrict__ out,
                         const int* __restrict__ cnt) {
  __shared__ __align__(16) float hs[256];
  const int tid = threadIdx.x;
  const int row = tid >> 1;   // 0..255
  const int kh = tid & 1;     // k-half
  float w_[128];
  {
    const float4* g = reinterpret_cast<const float4*>(lrw + (size_t)row * 256 + kh * 128);
#pragma unroll
    for (int q = 0; q < 32; ++q) {
      float4 v = g[q];
      w_[4 * q + 0] = v.x; w_[4 * q + 1] = v.y; w_[4 * q + 2] = v.z; w_[4 * q + 3] = v.w;
    }
  }
  const float bias = lrb[row];
  const int* prev = &cnt[3 * CNT_STRIDE];
  int rdy = 0;
  for (int t = 0; t < 512; ++t) {
    wait_ge(prev, t + 1, rdy);
    if (tid < 128) {
      uint64_t hv = ldg_u64(h3 + t * 256 + 2 * tid);  // device-coherent 8B
      uint2 u;
      u.x = (uint32_t)hv;
      u.y = (uint32_t)(hv >> 32);
      *reinterpret_cast<uint2*>(&hs[2 * tid]) = u;  // ds_write_b64, conflict-free
    }
    __syncthreads();
    float a0 = 0.f, a1 = 0.f;
    const float* hp = hs + kh * 128;
#pragma unroll
    for (int k = 0; k < 128; k += 4) {
      a0 += w_[k] * hp[k] + w_[k + 2] * hp[k + 2];
      a1 += w_[k + 1] * hp[k + 1] + w_[k + 3] * hp[k + 3];
    }
    float s = a0 + a1;
    s += __shfl_xor(s, 1);  // combine k-halves
    if (!kh) out[t * 256 + row] = s + bias;  // plain store, d_out
    __syncthreads();  // hs reads done before next overwrite
  }
}

// grid.x = 11:
// 0=scan0 | 1,2=proj1 | 3=scan1 | 4,5=proj2 | 6=scan2 | 7,8=proj3 | 9=scan3 | 10=final
__global__ __launch_bounds__(512, 2) void pipeline(
    const float* __restrict__ whh0, const float* __restrict__ whh1,
    const float* __restrict__ whh2, const float* __restrict__ whh3,
    const float* __restrict__ wih1, const float* __restrict__ wih2,
    const float* __restrict__ wih3,
    const float* __restrict__ xg0, float* __restrict__ xgp,
    float* __restrict__ hseq,
    const float* __restrict__ bih1, const float* __restrict__ bhh1,
    const float* __restrict__ bih2, const float* __restrict__ bhh2,
    const float* __restrict__ bih3, const float* __restrict__ bhh3,
    const float* __restrict__ lrw, const float* __restrict__ lrb,
    float* __restrict__ out, int* __restrict__ cnt) {
  const int bx = blockIdx.x;
  if (bx == 0) {
    scan_fn(0, whh0, xg0, hseq, cnt);
  } else if (bx == 10) {
    final_fn(lrw, lrb, hseq + (size_t)3 * 131072, out, cnt);
  } else {
    const int g = bx - 1;
    const int l = g / 3 + 1;
    const int r = g % 3;
    const float* whh = (l == 1) ? whh1 : (l == 2) ? whh2 : whh3;
    const float* wih = (l == 1) ? wih1 : (l == 2) ? wih2 : wih3;
    const float* bih = (l == 1) ? bih1 : (l == 2) ? bih2 : bih3;
    const float* bhh = (l == 1) ? bhh1 : (l == 2) ? bhh2 : bhh3;
    if (r < 2)
      proj_fn(l, r, wih, bih, bhh,
              hseq + (size_t)(l - 1) * 131072, xgp + (size_t)(l - 1) * 524288, cnt);
    else
      scan_fn(l, whh, xgp + (size_t)(l - 1) * 524288,
              hseq + (size_t)l * 131072, cnt);
  }
}

extern "C" void kernel_launch(void* const* d_in, const int* in_sizes, int n_in,
                              void* d_out, int out_size, void* d_ws, size_t ws_size,
                              hipStream_t stream) {
  (void)in_sizes; (void)n_in; (void)out_size; (void)ws_size;
  const float* x = (const float*)d_in[0];
  const float* wih[4] = {(const float*)d_in[1], (const float*)d_in[5],
                         (const float*)d_in[9], (const float*)d_in[13]};
  const float* whh[4] = {(const float*)d_in[2], (const float*)d_in[6],
                         (const float*)d_in[10], (const float*)d_in[14]};
  const float* bih[4] = {(const float*)d_in[3], (const float*)d_in[7],
                         (const float*)d_in[11], (const float*)d_in[15]};
  const float* bhh[4] = {(const float*)d_in[4], (const float*)d_in[8],
                         (const float*)d_in[12], (const float*)d_in[16]};
  const float* lrw = (const float*)d_in[17];
  const float* lrb = (const float*)d_in[18];
  float* out = (float*)d_out;

  // ws layout (4B units):
  //   xg0[524288] | xgp[3*524288] | hseq[4*131072] | cnt int[16*CNT_STRIDE]
  float* ws = (float*)d_ws;
  float* xg0 = ws;
  float* xgp = ws + 524288;
  float* hseq = xgp + 3 * 524288;
  int* cnt = (int*)(hseq + 4 * 131072);

  zero_cnt<<<1, 512, 0, stream>>>(cnt);

  // layer-0 projection from x (batch element 255)
  proj_gemm<<<dim3(4, 64), 256, 0, stream>>>(x + 255 * 512, 256 * 512, 512,
                                             wih[0], bih[0], bhh[0], xg0);

  pipeline<<<11, 512, 0, stream>>>(whh[0], whh[1], whh[2], whh[3],
                                   wih[1], wih[2], wih[3],
                                   xg0, xgp, hseq,
                                   bih[1], bhh[1], bih[2], bhh[2], bih[3], bhh[3],
                                   lrw, lrb, out, cnt);
}

// Round 9
// 1134.641 us; speedup vs baseline: 1.0563x; 1.0563x over previous
//
#include <hip/hip_runtime.h>
#include <stdint.h>

// ============================================================================
// LSTM stack, batch-sliced: reference returns out[:, -1] == batch element 255
// only -> single sequence (T=512) through 4 layers (H=256) + final linear.
//
// Round 9 = REVERT to round 7 (best measured: 1166.9us total / 1124.6 pipeline)
// + zero_cnt folded into proj_gemm block (0,0) (one fewer dispatch).
// Rounds 5/6/8 sync theories (poll restructure, startup slack, delayed store,
// fused packing) all null or negative -> round-7 config is the optimum of this
// structure. Known-benign: SQ_LDS_BANK_CONFLICT=524288 from final_fn's 2-way
// stride-128 LDS reads (2-way is ~free on gfx950).
// ============================================================================

typedef _Float16 half2v __attribute__((ext_vector_type(2)));

__device__ __forceinline__ float fdot2u(uint32_t w, uint32_t h, float acc) {
#if __has_builtin(__builtin_amdgcn_fdot2)
  return __builtin_amdgcn_fdot2(__builtin_bit_cast(half2v, w),
                                __builtin_bit_cast(half2v, h), acc, false);
#else
  half2v wv = __builtin_bit_cast(half2v, w);
  half2v hv = __builtin_bit_cast(half2v, h);
  acc += (float)wv[0] * (float)hv[0];
  acc += (float)wv[1] * (float)hv[1];
  return acc;
#endif
}

__device__ __forceinline__ float sigmoidf_(float x) {
  return 1.f / (1.f + __expf(-x));
}
__device__ __forceinline__ float tanhf_(float x) {
  return 1.f - 2.f / (__expf(2.f * x) + 1.f);  // exp overflow -> returns 1
}

#define CNT_STRIDE 32  // ints per counter slot = 128 B = 1 cacheline

__device__ __forceinline__ int cnt_load(const int* p) {
  return __hip_atomic_load(p, __ATOMIC_RELAXED, __HIP_MEMORY_SCOPE_AGENT);
}
__device__ __forceinline__ void cnt_store(int* p, int v) {
  __hip_atomic_store(p, v, __ATOMIC_RELAXED, __HIP_MEMORY_SCOPE_AGENT);
}
// device-coherent (sc0 sc1) data accesses -- no cache maintenance
__device__ __forceinline__ float ldg_f32(const float* p) {
  uint32_t u = __hip_atomic_load((const uint32_t*)p, __ATOMIC_RELAXED,
                                 __HIP_MEMORY_SCOPE_AGENT);
  return __builtin_bit_cast(float, u);
}
__device__ __forceinline__ void stg_f32(float* p, float v) {
  __hip_atomic_store((uint32_t*)p, __builtin_bit_cast(uint32_t, v),
                     __ATOMIC_RELAXED, __HIP_MEMORY_SCOPE_AGENT);
}
__device__ __forceinline__ uint64_t ldg_u64(const float* p) {
  return __hip_atomic_load((const uint64_t*)p, __ATOMIC_RELAXED,
                           __HIP_MEMORY_SCOPE_AGENT);
}

// spin until *p >= need; rdy caches the last observed value (monotone counter)
__device__ __forceinline__ void wait_ge(const int* p, int need, int& rdy) {
  while (rdy < need) {
    rdy = cnt_load(p);
    if (rdy < need) __builtin_amdgcn_s_sleep(2);
  }
  asm volatile("" ::: "memory");  // keep data loads below the poll (compiler)
}

// ---- pack all 7 1024x256 f32 matrices into u32 of 2xfp16, one dispatch.
// dst layout: wpkhh[4][131072] | wpkih[3][131072] (contiguous).
__global__ __launch_bounds__(256) void pack_all(
    const float* __restrict__ w0, const float* __restrict__ w1,
    const float* __restrict__ w2, const float* __restrict__ w3,
    const float* __restrict__ w4, const float* __restrict__ w5,
    const float* __restrict__ w6, uint32_t* __restrict__ dst) {
  int b = blockIdx.x;           // 0..3583, 512 blocks per matrix
  int m = b >> 9;               // matrix id 0..6
  const float* src = (m == 0) ? w0 : (m == 1) ? w1 : (m == 2) ? w2
                   : (m == 3) ? w3 : (m == 4) ? w4 : (m == 5) ? w5 : w6;
  uint32_t* d = dst + (size_t)m * 131072;
  int idx = (b & 511) * 256 + threadIdx.x;  // 0 .. 131071
  int r = idx >> 7, k2 = idx & 127;
  float f0 = src[r * 256 + 2 * k2];
  float f1 = src[r * 256 + 2 * k2 + 1];
  union { _Float16 h; uint16_t u; } a, bb;
  a.h = (_Float16)f0;
  bb.h = (_Float16)f1;
  d[idx] = (uint32_t)a.u | ((uint32_t)bb.u << 16);
}

// ---- layer-0 input projection (from x, fully parallel, f32).
// Block (0,0) also zeroes the sync counters (stream-ordered before pipeline).
__global__ __launch_bounds__(256) void proj_gemm(const float* __restrict__ in, int istride, int K,
                                                 const float* __restrict__ W,
                                                 const float* __restrict__ bih,
                                                 const float* __restrict__ bhh,
                                                 float* __restrict__ xg,
                                                 int* __restrict__ cnt) {
  if (blockIdx.x == 0 && blockIdx.y == 0) {
    if (threadIdx.x < 16 * CNT_STRIDE) cnt[threadIdx.x] = 0;
  }
  __shared__ float xs[8][512];
  const int tid = threadIdx.x;
  const int r = blockIdx.x * 256 + tid;
  const int t0 = blockIdx.y * 8;
  for (int tt = 0; tt < 8; ++tt)
    for (int k = tid; k < K; k += 256)
      xs[tt][k] = in[(size_t)(t0 + tt) * istride + k];
  __syncthreads();
  float bias = bih[r] + bhh[r];
  float acc[8];
#pragma unroll
  for (int j = 0; j < 8; ++j) acc[j] = bias;
  const float* wr = W + (size_t)r * K;
  for (int k = 0; k < K; k += 4) {
    float4 w4 = *reinterpret_cast<const float4*>(wr + k);
#pragma unroll
    for (int j = 0; j < 8; ++j)
      acc[j] += xs[j][k] * w4.x + xs[j][k + 1] * w4.y + xs[j][k + 2] * w4.z +
                xs[j][k + 3] * w4.w;
  }
#pragma unroll
  for (int j = 0; j < 8; ++j) xg[(size_t)(t0 + j) * 1024 + r] = acc[j];
}

// ============================ pipeline stages ===============================

// scan: round-4 proven body. 512 thr; thread 2j: rows (j, j+256);
// thread 2j+1: rows (j+512, j+768). cnt[l]=v <=> h(0..v-1) visible.
__device__ void scan_fn(int l, const uint32_t* __restrict__ wpk,
                        const float* __restrict__ xgsrc,
                        float* __restrict__ hseq, int* __restrict__ cnt) {
  __shared__ __align__(16) uint4 wlds[8 * 2 * 512];   // 128 KB
  __shared__ __align__(16) uint16_t hbuf[2][256];
  const int tid = threadIdx.x;
  const int j = tid >> 1;
  const int odd = tid & 1;
  const int rA = j + (odd ? 512 : 0);
  const int rB = rA + 256;

  uint32_t wA[96], wB[96];
  {
    const uint4* gA = reinterpret_cast<const uint4*>(wpk + rA * 128);
    const uint4* gB = reinterpret_cast<const uint4*>(wpk + rB * 128);
#pragma unroll
    for (int q = 0; q < 24; ++q) {
      uint4 a = gA[q];
      wA[4 * q + 0] = a.x; wA[4 * q + 1] = a.y; wA[4 * q + 2] = a.z; wA[4 * q + 3] = a.w;
      uint4 b = gB[q];
      wB[4 * q + 0] = b.x; wB[4 * q + 1] = b.y; wB[4 * q + 2] = b.z; wB[4 * q + 3] = b.w;
    }
#pragma unroll
    for (int c = 0; c < 8; ++c) {
      wlds[(c * 2 + 0) * 512 + tid] = gA[24 + c];
      wlds[(c * 2 + 1) * 512 + tid] = gB[24 + c];
    }
  }
  if (tid < 256) hbuf[0][tid] = 0;
  __syncthreads();

  const int* mycnt = &cnt[(4 + (l - 1) * 2 + odd) * CNT_STRIDE];
  int rdy = 0;
  if (l) wait_ge(mycnt, 1, rdy);
  float c_ = 0.f;
  float xga = ldg_f32(xgsrc + rA), xgb = ldg_f32(xgsrc + rB);
  int pp = 0;
  for (int t = 0; t < 512; ++t) {
    const int tn = (t < 511) ? (t + 1) : 511;
    if (l) {
      int need = (t + 2 > 512) ? 512 : (t + 2);
      wait_ge(mycnt, need, rdy);
    }
    float nxa = ldg_f32(xgsrc + tn * 1024 + rA);  // prefetch t+1
    float nxb = ldg_f32(xgsrc + tn * 1024 + rB);

    float accA0 = xga, accA1 = 0.f, accB0 = xgb, accB1 = 0.f;
    const uint4* hv4 = reinterpret_cast<const uint4*>(&hbuf[pp][0]);
#pragma unroll
    for (int ch = 0; ch < 24; ++ch) {
      uint4 h4 = hv4[ch];
      accA0 = fdot2u(wA[4 * ch + 0], h4.x, accA0);
      accA1 = fdot2u(wA[4 * ch + 1], h4.y, accA1);
      accA0 = fdot2u(wA[4 * ch + 2], h4.z, accA0);
      accA1 = fdot2u(wA[4 * ch + 3], h4.w, accA1);
      accB0 = fdot2u(wB[4 * ch + 0], h4.x, accB0);
      accB1 = fdot2u(wB[4 * ch + 1], h4.y, accB1);
      accB0 = fdot2u(wB[4 * ch + 2], h4.z, accB0);
      accB1 = fdot2u(wB[4 * ch + 3], h4.w, accB1);
    }
#pragma unroll
    for (int cc = 0; cc < 8; ++cc) {
      uint4 h4 = hv4[24 + cc];
      uint4 wa = wlds[(cc * 2 + 0) * 512 + tid];
      uint4 wb = wlds[(cc * 2 + 1) * 512 + tid];
      accA0 = fdot2u(wa.x, h4.x, accA0);
      accA1 = fdot2u(wa.y, h4.y, accA1);
      accA0 = fdot2u(wa.z, h4.z, accA0);
      accA1 = fdot2u(wa.w, h4.w, accA1);
      accB0 = fdot2u(wb.x, h4.x, accB0);
      accB1 = fdot2u(wb.y, h4.y, accB1);
      accB0 = fdot2u(wb.z, h4.z, accB0);
      accB1 = fdot2u(wb.w, h4.w, accB1);
    }
    float accA = accA0 + accA1;
    float accB = accB0 + accB1;

    float o0 = __shfl_xor(accA, 1);
    float o1 = __shfl_xor(accB, 1);
    float pi = odd ? o0 : accA;
    float pf = odd ? o1 : accB;
    float pg = odd ? accA : o0;
    float po = odd ? accB : o1;

    c_ = sigmoidf_(pf) * c_ + sigmoidf_(pi) * tanhf_(pg);
    float h = sigmoidf_(po) * tanhf_(c_);
    if (!odd) {
      stg_f32(hseq + t * 256 + j, h);  // device-coherent store
      union { _Float16 hf; uint16_t u; } cv;
      cv.hf = (_Float16)h;
      hbuf[pp ^ 1][j] = cv.u;
    }
    __syncthreads();  // vmcnt(0) drain + hbuf visible
    if (tid == 0) cnt_store(&cnt[l * CNT_STRIDE], t + 1);
    pp ^= 1;
    xga = nxa;
    xgb = nxb;
  }
}

// proj: 512 thr, WG owns rows [half*512, half*512+512), 1 row/thread.
// 4-step chunks: one poll + one batched h-load RTT + one store-drain RTT
// amortize over 4 steps.
__device__ void proj_fn(int l, int half, const uint32_t* __restrict__ wpk,
                        const float* __restrict__ bih, const float* __restrict__ bhh,
                        const float* __restrict__ hsrc,   // hseq layer l-1 (f32)
                        float* __restrict__ xgdst, int* __restrict__ cnt) {
  __shared__ __align__(16) uint32_t hpk[4][128];  // 4 steps of packed fp16 h
  const int tid = threadIdx.x;
  const int row = half * 512 + tid;

  uint32_t wr_[128];
  {
    const uint4* g = reinterpret_cast<const uint4*>(wpk + (size_t)row * 128);
#pragma unroll
    for (int q = 0; q < 32; ++q) {
      uint4 v = g[q];
      wr_[4 * q + 0] = v.x; wr_[4 * q + 1] = v.y; wr_[4 * q + 2] = v.z; wr_[4 * q + 3] = v.w;
    }
  }
  const float bias = bih[row] + bhh[row];
  const int* prev = &cnt[(l - 1) * CNT_STRIDE];
  int* mine = &cnt[(4 + (l - 1) * 2 + half) * CNT_STRIDE];
  int rdy = 0;
  const int s4 = tid >> 7;    // pack slot 0..3 (step within chunk)
  const int c4 = tid & 127;   // column pair

  for (int tt = 0; tt < 128; ++tt) {
    const int t0 = tt * 4;
    wait_ge(prev, t0 + 4, rdy);  // h(t0..t0+3) visible
    {
      uint64_t hv = ldg_u64(hsrc + (t0 + s4) * 256 + 2 * c4);  // one RTT, batched
      float hx = __builtin_bit_cast(float, (uint32_t)hv);
      float hy = __builtin_bit_cast(float, (uint32_t)(hv >> 32));
      union { _Float16 h; uint16_t u; } a, b;
      a.h = (_Float16)hx;
      b.h = (_Float16)hy;
      hpk[s4][c4] = (uint32_t)a.u | ((uint32_t)b.u << 16);
    }
    __syncthreads();  // 4 steps of h staged
#pragma unroll
    for (int s = 0; s < 4; ++s) {
      float a0 = bias, a1 = 0.f;
      const uint4* hv4 = reinterpret_cast<const uint4*>(hpk[s]);
#pragma unroll
      for (int q = 0; q < 32; ++q) {
        uint4 h4 = hv4[q];
        a0 = fdot2u(wr_[4 * q + 0], h4.x, a0);
        a1 = fdot2u(wr_[4 * q + 1], h4.y, a1);
        a0 = fdot2u(wr_[4 * q + 2], h4.z, a0);
        a1 = fdot2u(wr_[4 * q + 3], h4.w, a1);
      }
      stg_f32(xgdst + (t0 + s) * 1024 + row, a0 + a1);
    }
    __syncthreads();  // all 4 xg stores drained; hpk reads done
    if (tid == 0) cnt_store(mine, t0 + 4);  // xg(0..t0+3) ready
  }
}

// final linear, fused: streams cnt[3]. 2 threads/row, f32 weights in regs.
__device__ void final_fn(const float* __restrict__ lrw, const float* __restrict__ lrb,
                         const float* __restrict__ h3, float* __restrict__ out,
                         const int* __restrict__ cnt) {
  __shared__ __align__(16) float hs[256];
  const int tid = threadIdx.x;
  const int row = tid >> 1;   // 0..255
  const int kh = tid & 1;     // k-half
  float w_[128];
  {
    const float4* g = reinterpret_cast<const float4*>(lrw + (size_t)row * 256 + kh * 128);
#pragma unroll
    for (int q = 0; q < 32; ++q) {
      float4 v = g[q];
      w_[4 * q + 0] = v.x; w_[4 * q + 1] = v.y; w_[4 * q + 2] = v.z; w_[4 * q + 3] = v.w;
    }
  }
  const float bias = lrb[row];
  const int* prev = &cnt[3 * CNT_STRIDE];
  int rdy = 0;
  for (int t = 0; t < 512; ++t) {
    wait_ge(prev, t + 1, rdy);
    if (tid < 128) {
      uint64_t hv = ldg_u64(h3 + t * 256 + 2 * tid);  // device-coherent 8B
      hs[2 * tid] = __builtin_bit_cast(float, (uint32_t)hv);
      hs[2 * tid + 1] = __builtin_bit_cast(float, (uint32_t)(hv >> 32));
    }
    __syncthreads();
    float a0 = 0.f, a1 = 0.f;
    const float* hp = hs + kh * 128;
#pragma unroll
    for (int k = 0; k < 128; k += 4) {
      a0 += w_[k] * hp[k] + w_[k + 2] * hp[k + 2];
      a1 += w_[k + 1] * hp[k + 1] + w_[k + 3] * hp[k + 3];
    }
    float s = a0 + a1;
    s += __shfl_xor(s, 1);  // combine k-halves
    if (!kh) out[t * 256 + row] = s + bias;  // plain store, d_out
    __syncthreads();  // hs reads done before next overwrite
  }
}

// grid.x = 11:
// 0=scan0 | 1,2=proj1 | 3=scan1 | 4,5=proj2 | 6=scan2 | 7,8=proj3 | 9=scan3 | 10=final
__global__ __launch_bounds__(512, 2) void pipeline(
    const uint32_t* __restrict__ wpkhh, const uint32_t* __restrict__ wpkih,
    const float* __restrict__ xg0, float* __restrict__ xgp,
    float* __restrict__ hseq,
    const float* __restrict__ bih1, const float* __restrict__ bhh1,
    const float* __restrict__ bih2, const float* __restrict__ bhh2,
    const float* __restrict__ bih3, const float* __restrict__ bhh3,
    const float* __restrict__ lrw, const float* __restrict__ lrb,
    float* __restrict__ out, int* __restrict__ cnt) {
  const int bx = blockIdx.x;
  if (bx == 0) {
    scan_fn(0, wpkhh, xg0, hseq, cnt);
  } else if (bx == 10) {
    final_fn(lrw, lrb, hseq + (size_t)3 * 131072, out, cnt);
  } else {
    const int g = bx - 1;
    const int l = g / 3 + 1;
    const int r = g % 3;
    const float* bih = (l == 1) ? bih1 : (l == 2) ? bih2 : bih3;
    const float* bhh = (l == 1) ? bhh1 : (l == 2) ? bhh2 : bhh3;
    if (r < 2)
      proj_fn(l, r, wpkih + (size_t)(l - 1) * 131072, bih, bhh,
              hseq + (size_t)(l - 1) * 131072, xgp + (size_t)(l - 1) * 524288, cnt);
    else
      scan_fn(l, wpkhh + (size_t)l * 131072, xgp + (size_t)(l - 1) * 524288,
              hseq + (size_t)l * 131072, cnt);
  }
}

extern "C" void kernel_launch(void* const* d_in, const int* in_sizes, int n_in,
                              void* d_out, int out_size, void* d_ws, size_t ws_size,
                              hipStream_t stream) {
  (void)in_sizes; (void)n_in; (void)out_size; (void)ws_size;
  const float* x = (const float*)d_in[0];
  const float* wih[4] = {(const float*)d_in[1], (const float*)d_in[5],
                         (const float*)d_in[9], (const float*)d_in[13]};
  const float* whh[4] = {(const float*)d_in[2], (const float*)d_in[6],
                         (const float*)d_in[10], (const float*)d_in[14]};
  const float* bih[4] = {(const float*)d_in[3], (const float*)d_in[7],
                         (const float*)d_in[11], (const float*)d_in[15]};
  const float* bhh[4] = {(const float*)d_in[4], (const float*)d_in[8],
                         (const float*)d_in[12], (const float*)d_in[16]};
  const float* lrw = (const float*)d_in[17];
  const float* lrb = (const float*)d_in[18];
  float* out = (float*)d_out;

  // ws layout (4B units):
  //   xg0[524288] | xgp[3*524288] | hseq[4*131072] | wpkhh u32[4*131072]
  //   | wpkih u32[3*131072] | cnt int[16*CNT_STRIDE]      (~14.2 MB total)
  float* ws = (float*)d_ws;
  float* xg0 = ws;
  float* xgp = ws + 524288;
  float* hseq = xgp + 3 * 524288;
  uint32_t* wpkhh = (uint32_t*)(hseq + 4 * 131072);
  uint32_t* wpkih = wpkhh + 4 * 131072;
  int* cnt = (int*)(wpkih + 3 * 131072);

  // one dispatch packs whh[0..3] then wih[1..3] into the contiguous region
  pack_all<<<3584, 256, 0, stream>>>(whh[0], whh[1], whh[2], whh[3],
                                     wih[1], wih[2], wih[3], wpkhh);

  // layer-0 projection from x (batch element 255); block (0,0) zeroes cnt
  proj_gemm<<<dim3(4, 64), 256, 0, stream>>>(x + 255 * 512, 256 * 512, 512,
                                             wih[0], bih[0], bhh[0], xg0, cnt);

  pipeline<<<11, 512, 0, stream>>>(wpkhh, wpkih, xg0, xgp, hseq,
                                   bih[1], bhh[1], bih[2], bhh[2], bih[3], bhh[3],
                                   lrw, lrb, out, cnt);
}

// Round 10
// 1059.199 us; speedup vs baseline: 1.1316x; 1.0712x over previous
//
#include <hip/hip_runtime.h>
#include <stdint.h>

// ============================================================================
// LSTM stack, batch-sliced: reference returns out[:, -1] == batch element 255
// only -> single sequence (T=512) through 4 layers (H=256) + final linear.
//
// Round 10 = round 9 with a K-SPLIT scan inner loop.
//   Model (first to match measurement): scan step was DS-pipe issue-bound:
//   48 ds_read_b128/thread x 8 waves = 384 DS instr/CU x ~10.3cy = 3960cy
//   = measured standalone rate. K-split across thread pairs (even thread:
//   all 4 gate rows on K[0,128); odd: K[128,256); combine via 4 DPP
//   shfl_xor(1)) halves h-broadcast reads: 48 -> 32 DS instr/thread,
//   384 -> 256 per CU -> predicted scan rate ~2700cy/step.
//   fdot2 count unchanged (256/thread); weights: 192 u32 regs + 16 u32 LDS
//   per thread (same budget, re-partitioned to 4 row-halves).
//   proj/final/proj_gemm/pack_all byte-identical to round 9.
// ============================================================================

typedef _Float16 half2v __attribute__((ext_vector_type(2)));

__device__ __forceinline__ float fdot2u(uint32_t w, uint32_t h, float acc) {
#if __has_builtin(__builtin_amdgcn_fdot2)
  return __builtin_amdgcn_fdot2(__builtin_bit_cast(half2v, w),
                                __builtin_bit_cast(half2v, h), acc, false);
#else
  half2v wv = __builtin_bit_cast(half2v, w);
  half2v hv = __builtin_bit_cast(half2v, h);
  acc += (float)wv[0] * (float)hv[0];
  acc += (float)wv[1] * (float)hv[1];
  return acc;
#endif
}

__device__ __forceinline__ float sigmoidf_(float x) {
  return 1.f / (1.f + __expf(-x));
}
__device__ __forceinline__ float tanhf_(float x) {
  return 1.f - 2.f / (__expf(2.f * x) + 1.f);  // exp overflow -> returns 1
}

#define CNT_STRIDE 32  // ints per counter slot = 128 B = 1 cacheline

__device__ __forceinline__ int cnt_load(const int* p) {
  return __hip_atomic_load(p, __ATOMIC_RELAXED, __HIP_MEMORY_SCOPE_AGENT);
}
__device__ __forceinline__ void cnt_store(int* p, int v) {
  __hip_atomic_store(p, v, __ATOMIC_RELAXED, __HIP_MEMORY_SCOPE_AGENT);
}
// device-coherent (sc0 sc1) data accesses -- no cache maintenance
__device__ __forceinline__ float ldg_f32(const float* p) {
  uint32_t u = __hip_atomic_load((const uint32_t*)p, __ATOMIC_RELAXED,
                                 __HIP_MEMORY_SCOPE_AGENT);
  return __builtin_bit_cast(float, u);
}
__device__ __forceinline__ void stg_f32(float* p, float v) {
  __hip_atomic_store((uint32_t*)p, __builtin_bit_cast(uint32_t, v),
                     __ATOMIC_RELAXED, __HIP_MEMORY_SCOPE_AGENT);
}
__device__ __forceinline__ uint64_t ldg_u64(const float* p) {
  return __hip_atomic_load((const uint64_t*)p, __ATOMIC_RELAXED,
                           __HIP_MEMORY_SCOPE_AGENT);
}

// spin until *p >= need; rdy caches the last observed value (monotone counter)
__device__ __forceinline__ void wait_ge(const int* p, int need, int& rdy) {
  while (rdy < need) {
    rdy = cnt_load(p);
    if (rdy < need) __builtin_amdgcn_s_sleep(2);
  }
  asm volatile("" ::: "memory");  // keep data loads below the poll (compiler)
}

// ---- pack all 7 1024x256 f32 matrices into u32 of 2xfp16, one dispatch.
// dst layout: wpkhh[4][131072] | wpkih[3][131072] (contiguous).
__global__ __launch_bounds__(256) void pack_all(
    const float* __restrict__ w0, const float* __restrict__ w1,
    const float* __restrict__ w2, const float* __restrict__ w3,
    const float* __restrict__ w4, const float* __restrict__ w5,
    const float* __restrict__ w6, uint32_t* __restrict__ dst) {
  int b = blockIdx.x;           // 0..3583, 512 blocks per matrix
  int m = b >> 9;               // matrix id 0..6
  const float* src = (m == 0) ? w0 : (m == 1) ? w1 : (m == 2) ? w2
                   : (m == 3) ? w3 : (m == 4) ? w4 : (m == 5) ? w5 : w6;
  uint32_t* d = dst + (size_t)m * 131072;
  int idx = (b & 511) * 256 + threadIdx.x;  // 0 .. 131071
  int r = idx >> 7, k2 = idx & 127;
  float f0 = src[r * 256 + 2 * k2];
  float f1 = src[r * 256 + 2 * k2 + 1];
  union { _Float16 h; uint16_t u; } a, bb;
  a.h = (_Float16)f0;
  bb.h = (_Float16)f1;
  d[idx] = (uint32_t)a.u | ((uint32_t)bb.u << 16);
}

// ---- layer-0 input projection (from x, fully parallel, f32).
// Block (0,0) also zeroes the sync counters (stream-ordered before pipeline).
__global__ __launch_bounds__(256) void proj_gemm(const float* __restrict__ in, int istride, int K,
                                                 const float* __restrict__ W,
                                                 const float* __restrict__ bih,
                                                 const float* __restrict__ bhh,
                                                 float* __restrict__ xg,
                                                 int* __restrict__ cnt) {
  if (blockIdx.x == 0 && blockIdx.y == 0) {
    if (threadIdx.x < 16 * CNT_STRIDE) cnt[threadIdx.x] = 0;
  }
  __shared__ float xs[8][512];
  const int tid = threadIdx.x;
  const int r = blockIdx.x * 256 + tid;
  const int t0 = blockIdx.y * 8;
  for (int tt = 0; tt < 8; ++tt)
    for (int k = tid; k < K; k += 256)
      xs[tt][k] = in[(size_t)(t0 + tt) * istride + k];
  __syncthreads();
  float bias = bih[r] + bhh[r];
  float acc[8];
#pragma unroll
  for (int j = 0; j < 8; ++j) acc[j] = bias;
  const float* wr = W + (size_t)r * K;
  for (int k = 0; k < K; k += 4) {
    float4 w4 = *reinterpret_cast<const float4*>(wr + k);
#pragma unroll
    for (int j = 0; j < 8; ++j)
      acc[j] += xs[j][k] * w4.x + xs[j][k + 1] * w4.y + xs[j][k + 2] * w4.z +
                xs[j][k + 3] * w4.w;
  }
#pragma unroll
  for (int j = 0; j < 8; ++j) xg[(size_t)(t0 + j) * 1024 + r] = acc[j];
}

// ============================ pipeline stages ===============================

// scan (K-split): 512 thr; pair (2j, 2j+1) jointly owns gate rows
// {j, j+256, j+512, j+768}. Even thread: K[0,128); odd: K[128,256).
// Combine partials via DPP shfl_xor(1). cnt[l]=v <=> h(0..v-1) visible.
__device__ void scan_fn(int l, const uint32_t* __restrict__ wpk,
                        const float* __restrict__ xgsrc,
                        float* __restrict__ hseq, int* __restrict__ cnt) {
  __shared__ __align__(16) uint4 wlds[16 * 512];      // 128 KB: [(i*4+c)][tid]
  __shared__ __align__(16) uint16_t hbuf[2][256];
  const int tid = threadIdx.x;
  const int j = tid >> 1;
  const int odd = tid & 1;
  const int rA = j + (odd ? 512 : 0);   // xg rows this thread loads (as before)
  const int rB = rA + 256;
  const int ho = odd * 64;              // u32 offset of this thread's K-half

  // weights: 4 gate rows x this K-half; 48 u32/row-half in regs + 16 in LDS
  uint32_t w0[48], w1[48], w2[48], w3[48];
  {
    const uint4* g0 = reinterpret_cast<const uint4*>(wpk + (size_t)(j)       * 128 + ho);
    const uint4* g1 = reinterpret_cast<const uint4*>(wpk + (size_t)(j + 256) * 128 + ho);
    const uint4* g2 = reinterpret_cast<const uint4*>(wpk + (size_t)(j + 512) * 128 + ho);
    const uint4* g3 = reinterpret_cast<const uint4*>(wpk + (size_t)(j + 768) * 128 + ho);
#pragma unroll
    for (int q = 0; q < 12; ++q) {
      uint4 a = g0[q];
      w0[4 * q + 0] = a.x; w0[4 * q + 1] = a.y; w0[4 * q + 2] = a.z; w0[4 * q + 3] = a.w;
      uint4 b = g1[q];
      w1[4 * q + 0] = b.x; w1[4 * q + 1] = b.y; w1[4 * q + 2] = b.z; w1[4 * q + 3] = b.w;
      uint4 c = g2[q];
      w2[4 * q + 0] = c.x; w2[4 * q + 1] = c.y; w2[4 * q + 2] = c.z; w2[4 * q + 3] = c.w;
      uint4 d = g3[q];
      w3[4 * q + 0] = d.x; w3[4 * q + 1] = d.y; w3[4 * q + 2] = d.z; w3[4 * q + 3] = d.w;
    }
#pragma unroll
    for (int c = 0; c < 4; ++c) {
      wlds[(0 * 4 + c) * 512 + tid] = g0[12 + c];
      wlds[(1 * 4 + c) * 512 + tid] = g1[12 + c];
      wlds[(2 * 4 + c) * 512 + tid] = g2[12 + c];
      wlds[(3 * 4 + c) * 512 + tid] = g3[12 + c];
    }
  }
  if (tid < 256) hbuf[0][tid] = 0;
  __syncthreads();

  const int* mycnt = &cnt[(4 + (l - 1) * 2 + odd) * CNT_STRIDE];
  int rdy = 0;
  if (l) wait_ge(mycnt, 1, rdy);
  float c_ = 0.f;
  float xga = ldg_f32(xgsrc + rA), xgb = ldg_f32(xgsrc + rB);
  int pp = 0;
  for (int t = 0; t < 512; ++t) {
    const int tn = (t < 511) ? (t + 1) : 511;
    if (l) {
      int need = (t + 2 > 512) ? 512 : (t + 2);
      wait_ge(mycnt, need, rdy);
    }
    float nxa = ldg_f32(xgsrc + tn * 1024 + rA);  // prefetch t+1
    float nxb = ldg_f32(xgsrc + tn * 1024 + rB);

    float a00 = 0.f, a01 = 0.f, a10 = 0.f, a11 = 0.f;
    float a20 = 0.f, a21 = 0.f, a30 = 0.f, a31 = 0.f;
    // this thread's K-half of h: 16 x b128 (was 32)
    const uint4* hv4 = reinterpret_cast<const uint4*>(&hbuf[pp][odd * 128]);
#pragma unroll
    for (int q = 0; q < 12; ++q) {
      uint4 h4 = hv4[q];
      a00 = fdot2u(w0[4 * q + 0], h4.x, a00);
      a01 = fdot2u(w0[4 * q + 1], h4.y, a01);
      a00 = fdot2u(w0[4 * q + 2], h4.z, a00);
      a01 = fdot2u(w0[4 * q + 3], h4.w, a01);
      a10 = fdot2u(w1[4 * q + 0], h4.x, a10);
      a11 = fdot2u(w1[4 * q + 1], h4.y, a11);
      a10 = fdot2u(w1[4 * q + 2], h4.z, a10);
      a11 = fdot2u(w1[4 * q + 3], h4.w, a11);
      a20 = fdot2u(w2[4 * q + 0], h4.x, a20);
      a21 = fdot2u(w2[4 * q + 1], h4.y, a21);
      a20 = fdot2u(w2[4 * q + 2], h4.z, a20);
      a21 = fdot2u(w2[4 * q + 3], h4.w, a21);
      a30 = fdot2u(w3[4 * q + 0], h4.x, a30);
      a31 = fdot2u(w3[4 * q + 1], h4.y, a31);
      a30 = fdot2u(w3[4 * q + 2], h4.z, a30);
      a31 = fdot2u(w3[4 * q + 3], h4.w, a31);
    }
#pragma unroll
    for (int c = 0; c < 4; ++c) {
      uint4 h4 = hv4[12 + c];
      uint4 v0 = wlds[(0 * 4 + c) * 512 + tid];
      a00 = fdot2u(v0.x, h4.x, a00);
      a01 = fdot2u(v0.y, h4.y, a01);
      a00 = fdot2u(v0.z, h4.z, a00);
      a01 = fdot2u(v0.w, h4.w, a01);
      uint4 v1 = wlds[(1 * 4 + c) * 512 + tid];
      a10 = fdot2u(v1.x, h4.x, a10);
      a11 = fdot2u(v1.y, h4.y, a11);
      a10 = fdot2u(v1.z, h4.z, a10);
      a11 = fdot2u(v1.w, h4.w, a11);
      uint4 v2 = wlds[(2 * 4 + c) * 512 + tid];
      a20 = fdot2u(v2.x, h4.x, a20);
      a21 = fdot2u(v2.y, h4.y, a21);
      a20 = fdot2u(v2.z, h4.z, a20);
      a21 = fdot2u(v2.w, h4.w, a21);
      uint4 v3 = wlds[(3 * 4 + c) * 512 + tid];
      a30 = fdot2u(v3.x, h4.x, a30);
      a31 = fdot2u(v3.y, h4.y, a31);
      a30 = fdot2u(v3.z, h4.z, a30);
      a31 = fdot2u(v3.w, h4.w, a31);
    }
    // fold this thread's xg rows into the matching gate partials, then
    // cross-pair reduce (partner holds the other K-half)
    float p0 = a00 + a01 + (odd ? 0.f : xga);   // gate i  (row j)
    float p1 = a10 + a11 + (odd ? 0.f : xgb);   // gate f  (row j+256)
    float p2 = a20 + a21 + (odd ? xga : 0.f);   // gate g  (row j+512)
    float p3 = a30 + a31 + (odd ? xgb : 0.f);   // gate o  (row j+768)
    float s0 = p0 + __shfl_xor(p0, 1);
    float s1 = p1 + __shfl_xor(p1, 1);
    float s2 = p2 + __shfl_xor(p2, 1);
    float s3 = p3 + __shfl_xor(p3, 1);

    c_ = sigmoidf_(s1) * c_ + sigmoidf_(s0) * tanhf_(s2);
    float h = sigmoidf_(s3) * tanhf_(c_);
    if (!odd) {
      stg_f32(hseq + t * 256 + j, h);  // device-coherent store
      union { _Float16 hf; uint16_t u; } cv;
      cv.hf = (_Float16)h;
      hbuf[pp ^ 1][j] = cv.u;
    }
    __syncthreads();  // vmcnt(0) drain + hbuf visible
    if (tid == 0) cnt_store(&cnt[l * CNT_STRIDE], t + 1);
    pp ^= 1;
    xga = nxa;
    xgb = nxb;
  }
}

// proj: 512 thr, WG owns rows [half*512, half*512+512), 1 row/thread.
// 4-step chunks: one poll + one batched h-load RTT + one store-drain RTT
// amortize over 4 steps.
__device__ void proj_fn(int l, int half, const uint32_t* __restrict__ wpk,
                        const float* __restrict__ bih, const float* __restrict__ bhh,
                        const float* __restrict__ hsrc,   // hseq layer l-1 (f32)
                        float* __restrict__ xgdst, int* __restrict__ cnt) {
  __shared__ __align__(16) uint32_t hpk[4][128];  // 4 steps of packed fp16 h
  const int tid = threadIdx.x;
  const int row = half * 512 + tid;

  uint32_t wr_[128];
  {
    const uint4* g = reinterpret_cast<const uint4*>(wpk + (size_t)row * 128);
#pragma unroll
    for (int q = 0; q < 32; ++q) {
      uint4 v = g[q];
      wr_[4 * q + 0] = v.x; wr_[4 * q + 1] = v.y; wr_[4 * q + 2] = v.z; wr_[4 * q + 3] = v.w;
    }
  }
  const float bias = bih[row] + bhh[row];
  const int* prev = &cnt[(l - 1) * CNT_STRIDE];
  int* mine = &cnt[(4 + (l - 1) * 2 + half) * CNT_STRIDE];
  int rdy = 0;
  const int s4 = tid >> 7;    // pack slot 0..3 (step within chunk)
  const int c4 = tid & 127;   // column pair

  for (int tt = 0; tt < 128; ++tt) {
    const int t0 = tt * 4;
    wait_ge(prev, t0 + 4, rdy);  // h(t0..t0+3) visible
    {
      uint64_t hv = ldg_u64(hsrc + (t0 + s4) * 256 + 2 * c4);  // one RTT, batched
      float hx = __builtin_bit_cast(float, (uint32_t)hv);
      float hy = __builtin_bit_cast(float, (uint32_t)(hv >> 32));
      union { _Float16 h; uint16_t u; } a, b;
      a.h = (_Float16)hx;
      b.h = (_Float16)hy;
      hpk[s4][c4] = (uint32_t)a.u | ((uint32_t)b.u << 16);
    }
    __syncthreads();  // 4 steps of h staged
#pragma unroll
    for (int s = 0; s < 4; ++s) {
      float a0 = bias, a1 = 0.f;
      const uint4* hv4 = reinterpret_cast<const uint4*>(hpk[s]);
#pragma unroll
      for (int q = 0; q < 32; ++q) {
        uint4 h4 = hv4[q];
        a0 = fdot2u(wr_[4 * q + 0], h4.x, a0);
        a1 = fdot2u(wr_[4 * q + 1], h4.y, a1);
        a0 = fdot2u(wr_[4 * q + 2], h4.z, a0);
        a1 = fdot2u(wr_[4 * q + 3], h4.w, a1);
      }
      stg_f32(xgdst + (t0 + s) * 1024 + row, a0 + a1);
    }
    __syncthreads();  // all 4 xg stores drained; hpk reads done
    if (tid == 0) cnt_store(mine, t0 + 4);  // xg(0..t0+3) ready
  }
}

// final linear, fused: streams cnt[3]. 2 threads/row, f32 weights in regs.
__device__ void final_fn(const float* __restrict__ lrw, const float* __restrict__ lrb,
                         const float* __restrict__ h3, float* __restrict__ out,
                         const int* __restrict__ cnt) {
  __shared__ __align__(16) float hs[256];
  const int tid = threadIdx.x;
  const int row = tid >> 1;   // 0..255
  const int kh = tid & 1;     // k-half
  float w_[128];
  {
    const float4* g = reinterpret_cast<const float4*>(lrw + (size_t)row * 256 + kh * 128);
#pragma unroll
    for (int q = 0; q < 32; ++q) {
      float4 v = g[q];
      w_[4 * q + 0] = v.x; w_[4 * q + 1] = v.y; w_[4 * q + 2] = v.z; w_[4 * q + 3] = v.w;
    }
  }
  const float bias = lrb[row];
  const int* prev = &cnt[3 * CNT_STRIDE];
  int rdy = 0;
  for (int t = 0; t < 512; ++t) {
    wait_ge(prev, t + 1, rdy);
    if (tid < 128) {
      uint64_t hv = ldg_u64(h3 + t * 256 + 2 * tid);  // device-coherent 8B
      hs[2 * tid] = __builtin_bit_cast(float, (uint32_t)hv);
      hs[2 * tid + 1] = __builtin_bit_cast(float, (uint32_t)(hv >> 32));
    }
    __syncthreads();
    float a0 = 0.f, a1 = 0.f;
    const float* hp = hs + kh * 128;
#pragma unroll
    for (int k = 0; k < 128; k += 4) {
      a0 += w_[k] * hp[k] + w_[k + 2] * hp[k + 2];
      a1 += w_[k + 1] * hp[k + 1] + w_[k + 3] * hp[k + 3];
    }
    float s = a0 + a1;
    s += __shfl_xor(s, 1);  // combine k-halves
    if (!kh) out[t * 256 + row] = s + bias;  // plain store, d_out
    __syncthreads();  // hs reads done before next overwrite
  }
}

// grid.x = 11:
// 0=scan0 | 1,2=proj1 | 3=scan1 | 4,5=proj2 | 6=scan2 | 7,8=proj3 | 9=scan3 | 10=final
__global__ __launch_bounds__(512, 2) void pipeline(
    const uint32_t* __restrict__ wpkhh, const uint32_t* __restrict__ wpkih,
    const float* __restrict__ xg0, float* __restrict__ xgp,
    float* __restrict__ hseq,
    const float* __restrict__ bih1, const float* __restrict__ bhh1,
    const float* __restrict__ bih2, const float* __restrict__ bhh2,
    const float* __restrict__ bih3, const float* __restrict__ bhh3,
    const float* __restrict__ lrw, const float* __restrict__ lrb,
    float* __restrict__ out, int* __restrict__ cnt) {
  const int bx = blockIdx.x;
  if (bx == 0) {
    scan_fn(0, wpkhh, xg0, hseq, cnt);
  } else if (bx == 10) {
    final_fn(lrw, lrb, hseq + (size_t)3 * 131072, out, cnt);
  } else {
    const int g = bx - 1;
    const int l = g / 3 + 1;
    const int r = g % 3;
    const float* bih = (l == 1) ? bih1 : (l == 2) ? bih2 : bih3;
    const float* bhh = (l == 1) ? bhh1 : (l == 2) ? bhh2 : bhh3;
    if (r < 2)
      proj_fn(l, r, wpkih + (size_t)(l - 1) * 131072, bih, bhh,
              hseq + (size_t)(l - 1) * 131072, xgp + (size_t)(l - 1) * 524288, cnt);
    else
      scan_fn(l, wpkhh + (size_t)l * 131072, xgp + (size_t)(l - 1) * 524288,
              hseq + (size_t)l * 131072, cnt);
  }
}

extern "C" void kernel_launch(void* const* d_in, const int* in_sizes, int n_in,
                              void* d_out, int out_size, void* d_ws, size_t ws_size,
                              hipStream_t stream) {
  (void)in_sizes; (void)n_in; (void)out_size; (void)ws_size;
  const float* x = (const float*)d_in[0];
  const float* wih[4] = {(const float*)d_in[1], (const float*)d_in[5],
                         (const float*)d_in[9], (const float*)d_in[13]};
  const float* whh[4] = {(const float*)d_in[2], (const float*)d_in[6],
                         (const float*)d_in[10], (const float*)d_in[14]};
  const float* bih[4] = {(const float*)d_in[3], (const float*)d_in[7],
                         (const float*)d_in[11], (const float*)d_in[15]};
  const float* bhh[4] = {(const float*)d_in[4], (const float*)d_in[8],
                         (const float*)d_in[12], (const float*)d_in[16]};
  const float* lrw = (const float*)d_in[17];
  const float* lrb = (const float*)d_in[18];
  float* out = (float*)d_out;

  // ws layout (4B units):
  //   xg0[524288] | xgp[3*524288] | hseq[4*131072] | wpkhh u32[4*131072]
  //   | wpkih u32[3*131072] | cnt int[16*CNT_STRIDE]      (~14.2 MB total)
  float* ws = (float*)d_ws;
  float* xg0 = ws;
  float* xgp = ws + 524288;
  float* hseq = xgp + 3 * 524288;
  uint32_t* wpkhh = (uint32_t*)(hseq + 4 * 131072);
  uint32_t* wpkih = wpkhh + 4 * 131072;
  int* cnt = (int*)(wpkih + 3 * 131072);

  // one dispatch packs whh[0..3] then wih[1..3] into the contiguous region
  pack_all<<<3584, 256, 0, stream>>>(whh[0], whh[1], whh[2], whh[3],
                                     wih[1], wih[2], wih[3], wpkhh);

  // layer-0 projection from x (batch element 255); block (0,0) zeroes cnt
  proj_gemm<<<dim3(4, 64), 256, 0, stream>>>(x + 255 * 512, 256 * 512, 512,
                                             wih[0], bih[0], bhh[0], xg0, cnt);

  pipeline<<<11, 512, 0, stream>>>(wpkhh, wpkih, xg0, xgp, hseq,
                                   bih[1], bhh[1], bih[2], bhh[2], bih[3], bhh[3],
                                   lrw, lrb, out, cnt);
}

// Round 11
// 1037.681 us; speedup vs baseline: 1.1550x; 1.0207x over previous
//
#include <hip/hip_runtime.h>
#include <stdint.h>

// ============================================================================
// LSTM stack, batch-sliced: reference returns out[:, -1] == batch element 255
// only -> single sequence (T=512) through 4 layers (H=256) + final linear.
//
// Round 11 = round 10 (K-split scan, 1059us) + LDS bank-offset fixes.
//   Round 10's K-split read &hbuf[odd*128]: even lanes at X, odd at X+256B.
//   256 % 128(bank period) == 0 -> both broadcast addresses hit the SAME 4
//   banks -> every hbuf b128 read serialized (conflicts 0.5M -> 1.57M).
//   Fix: odd K-half stored at +16B skew (element 136 of hbuf[2][272]) ->
//   even lanes use banks {4c..4c+3}, odd {4c+4..4c+7} -> disjoint, 0 conflict.
//   Same fix in final_fn (hs[260], odd half at element 132).
//   Everything else byte-identical to round 10.
// ============================================================================

typedef _Float16 half2v __attribute__((ext_vector_type(2)));

__device__ __forceinline__ float fdot2u(uint32_t w, uint32_t h, float acc) {
#if __has_builtin(__builtin_amdgcn_fdot2)
  return __builtin_amdgcn_fdot2(__builtin_bit_cast(half2v, w),
                                __builtin_bit_cast(half2v, h), acc, false);
#else
  half2v wv = __builtin_bit_cast(half2v, w);
  half2v hv = __builtin_bit_cast(half2v, h);
  acc += (float)wv[0] * (float)hv[0];
  acc += (float)wv[1] * (float)hv[1];
  return acc;
#endif
}

__device__ __forceinline__ float sigmoidf_(float x) {
  return 1.f / (1.f + __expf(-x));
}
__device__ __forceinline__ float tanhf_(float x) {
  return 1.f - 2.f / (__expf(2.f * x) + 1.f);  // exp overflow -> returns 1
}

#define CNT_STRIDE 32  // ints per counter slot = 128 B = 1 cacheline

__device__ __forceinline__ int cnt_load(const int* p) {
  return __hip_atomic_load(p, __ATOMIC_RELAXED, __HIP_MEMORY_SCOPE_AGENT);
}
__device__ __forceinline__ void cnt_store(int* p, int v) {
  __hip_atomic_store(p, v, __ATOMIC_RELAXED, __HIP_MEMORY_SCOPE_AGENT);
}
// device-coherent (sc0 sc1) data accesses -- no cache maintenance
__device__ __forceinline__ float ldg_f32(const float* p) {
  uint32_t u = __hip_atomic_load((const uint32_t*)p, __ATOMIC_RELAXED,
                                 __HIP_MEMORY_SCOPE_AGENT);
  return __builtin_bit_cast(float, u);
}
__device__ __forceinline__ void stg_f32(float* p, float v) {
  __hip_atomic_store((uint32_t*)p, __builtin_bit_cast(uint32_t, v),
                     __ATOMIC_RELAXED, __HIP_MEMORY_SCOPE_AGENT);
}
__device__ __forceinline__ uint64_t ldg_u64(const float* p) {
  return __hip_atomic_load((const uint64_t*)p, __ATOMIC_RELAXED,
                           __HIP_MEMORY_SCOPE_AGENT);
}

// spin until *p >= need; rdy caches the last observed value (monotone counter)
__device__ __forceinline__ void wait_ge(const int* p, int need, int& rdy) {
  while (rdy < need) {
    rdy = cnt_load(p);
    if (rdy < need) __builtin_amdgcn_s_sleep(2);
  }
  asm volatile("" ::: "memory");  // keep data loads below the poll (compiler)
}

// ---- pack all 7 1024x256 f32 matrices into u32 of 2xfp16, one dispatch.
// dst layout: wpkhh[4][131072] | wpkih[3][131072] (contiguous).
__global__ __launch_bounds__(256) void pack_all(
    const float* __restrict__ w0, const float* __restrict__ w1,
    const float* __restrict__ w2, const float* __restrict__ w3,
    const float* __restrict__ w4, const float* __restrict__ w5,
    const float* __restrict__ w6, uint32_t* __restrict__ dst) {
  int b = blockIdx.x;           // 0..3583, 512 blocks per matrix
  int m = b >> 9;               // matrix id 0..6
  const float* src = (m == 0) ? w0 : (m == 1) ? w1 : (m == 2) ? w2
                   : (m == 3) ? w3 : (m == 4) ? w4 : (m == 5) ? w5 : w6;
  uint32_t* d = dst + (size_t)m * 131072;
  int idx = (b & 511) * 256 + threadIdx.x;  // 0 .. 131071
  int r = idx >> 7, k2 = idx & 127;
  float f0 = src[r * 256 + 2 * k2];
  float f1 = src[r * 256 + 2 * k2 + 1];
  union { _Float16 h; uint16_t u; } a, bb;
  a.h = (_Float16)f0;
  bb.h = (_Float16)f1;
  d[idx] = (uint32_t)a.u | ((uint32_t)bb.u << 16);
}

// ---- layer-0 input projection (from x, fully parallel, f32).
// Block (0,0) also zeroes the sync counters (stream-ordered before pipeline).
__global__ __launch_bounds__(256) void proj_gemm(const float* __restrict__ in, int istride, int K,
                                                 const float* __restrict__ W,
                                                 const float* __restrict__ bih,
                                                 const float* __restrict__ bhh,
                                                 float* __restrict__ xg,
                                                 int* __restrict__ cnt) {
  if (blockIdx.x == 0 && blockIdx.y == 0) {
    if (threadIdx.x < 16 * CNT_STRIDE) cnt[threadIdx.x] = 0;
  }
  __shared__ float xs[8][512];
  const int tid = threadIdx.x;
  const int r = blockIdx.x * 256 + tid;
  const int t0 = blockIdx.y * 8;
  for (int tt = 0; tt < 8; ++tt)
    for (int k = tid; k < K; k += 256)
      xs[tt][k] = in[(size_t)(t0 + tt) * istride + k];
  __syncthreads();
  float bias = bih[r] + bhh[r];
  float acc[8];
#pragma unroll
  for (int j = 0; j < 8; ++j) acc[j] = bias;
  const float* wr = W + (size_t)r * K;
  for (int k = 0; k < K; k += 4) {
    float4 w4 = *reinterpret_cast<const float4*>(wr + k);
#pragma unroll
    for (int j = 0; j < 8; ++j)
      acc[j] += xs[j][k] * w4.x + xs[j][k + 1] * w4.y + xs[j][k + 2] * w4.z +
                xs[j][k + 3] * w4.w;
  }
#pragma unroll
  for (int j = 0; j < 8; ++j) xg[(size_t)(t0 + j) * 1024 + r] = acc[j];
}

// ============================ pipeline stages ===============================

// scan (K-split): 512 thr; pair (2j, 2j+1) jointly owns gate rows
// {j, j+256, j+512, j+768}. Even thread: K[0,128); odd: K[128,256).
// hbuf odd half at +16B bank skew (element 136) -> conflict-free 2-addr reads.
// Combine partials via DPP shfl_xor(1). cnt[l]=v <=> h(0..v-1) visible.
__device__ void scan_fn(int l, const uint32_t* __restrict__ wpk,
                        const float* __restrict__ xgsrc,
                        float* __restrict__ hseq, int* __restrict__ cnt) {
  __shared__ __align__(16) uint4 wlds[16 * 512];      // 128 KB: [(i*4+c)][tid]
  __shared__ __align__(16) uint16_t hbuf[2][272];     // odd K-half at elem 136
  const int tid = threadIdx.x;
  const int j = tid >> 1;
  const int odd = tid & 1;
  const int rA = j + (odd ? 512 : 0);   // xg rows this thread loads
  const int rB = rA + 256;
  const int ho = odd * 64;              // u32 offset of this thread's K-half

  // weights: 4 gate rows x this K-half; 48 u32/row-half in regs + 16 in LDS
  uint32_t w0[48], w1[48], w2[48], w3[48];
  {
    const uint4* g0 = reinterpret_cast<const uint4*>(wpk + (size_t)(j)       * 128 + ho);
    const uint4* g1 = reinterpret_cast<const uint4*>(wpk + (size_t)(j + 256) * 128 + ho);
    const uint4* g2 = reinterpret_cast<const uint4*>(wpk + (size_t)(j + 512) * 128 + ho);
    const uint4* g3 = reinterpret_cast<const uint4*>(wpk + (size_t)(j + 768) * 128 + ho);
#pragma unroll
    for (int q = 0; q < 12; ++q) {
      uint4 a = g0[q];
      w0[4 * q + 0] = a.x; w0[4 * q + 1] = a.y; w0[4 * q + 2] = a.z; w0[4 * q + 3] = a.w;
      uint4 b = g1[q];
      w1[4 * q + 0] = b.x; w1[4 * q + 1] = b.y; w1[4 * q + 2] = b.z; w1[4 * q + 3] = b.w;
      uint4 c = g2[q];
      w2[4 * q + 0] = c.x; w2[4 * q + 1] = c.y; w2[4 * q + 2] = c.z; w2[4 * q + 3] = c.w;
      uint4 d = g3[q];
      w3[4 * q + 0] = d.x; w3[4 * q + 1] = d.y; w3[4 * q + 2] = d.z; w3[4 * q + 3] = d.w;
    }
#pragma unroll
    for (int c = 0; c < 4; ++c) {
      wlds[(0 * 4 + c) * 512 + tid] = g0[12 + c];
      wlds[(1 * 4 + c) * 512 + tid] = g1[12 + c];
      wlds[(2 * 4 + c) * 512 + tid] = g2[12 + c];
      wlds[(3 * 4 + c) * 512 + tid] = g3[12 + c];
    }
  }
  if (tid < 272) hbuf[0][tid] = 0;
  __syncthreads();

  const int* mycnt = &cnt[(4 + (l - 1) * 2 + odd) * CNT_STRIDE];
  int rdy = 0;
  if (l) wait_ge(mycnt, 1, rdy);
  float c_ = 0.f;
  float xga = ldg_f32(xgsrc + rA), xgb = ldg_f32(xgsrc + rB);
  int pp = 0;
  for (int t = 0; t < 512; ++t) {
    const int tn = (t < 511) ? (t + 1) : 511;
    if (l) {
      int need = (t + 2 > 512) ? 512 : (t + 2);
      wait_ge(mycnt, need, rdy);
    }
    float nxa = ldg_f32(xgsrc + tn * 1024 + rA);  // prefetch t+1
    float nxb = ldg_f32(xgsrc + tn * 1024 + rB);

    float a00 = 0.f, a01 = 0.f, a10 = 0.f, a11 = 0.f;
    float a20 = 0.f, a21 = 0.f, a30 = 0.f, a31 = 0.f;
    // this thread's K-half of h: 16 x b128; odd half bank-skewed (+16B)
    const uint4* hv4 = reinterpret_cast<const uint4*>(&hbuf[pp][odd * 136]);
#pragma unroll
    for (int q = 0; q < 12; ++q) {
      uint4 h4 = hv4[q];
      a00 = fdot2u(w0[4 * q + 0], h4.x, a00);
      a01 = fdot2u(w0[4 * q + 1], h4.y, a01);
      a00 = fdot2u(w0[4 * q + 2], h4.z, a00);
      a01 = fdot2u(w0[4 * q + 3], h4.w, a01);
      a10 = fdot2u(w1[4 * q + 0], h4.x, a10);
      a11 = fdot2u(w1[4 * q + 1], h4.y, a11);
      a10 = fdot2u(w1[4 * q + 2], h4.z, a10);
      a11 = fdot2u(w1[4 * q + 3], h4.w, a11);
      a20 = fdot2u(w2[4 * q + 0], h4.x, a20);
      a21 = fdot2u(w2[4 * q + 1], h4.y, a21);
      a20 = fdot2u(w2[4 * q + 2], h4.z, a20);
      a21 = fdot2u(w2[4 * q + 3], h4.w, a21);
      a30 = fdot2u(w3[4 * q + 0], h4.x, a30);
      a31 = fdot2u(w3[4 * q + 1], h4.y, a31);
      a30 = fdot2u(w3[4 * q + 2], h4.z, a30);
      a31 = fdot2u(w3[4 * q + 3], h4.w, a31);
    }
#pragma unroll
    for (int c = 0; c < 4; ++c) {
      uint4 h4 = hv4[12 + c];
      uint4 v0 = wlds[(0 * 4 + c) * 512 + tid];
      a00 = fdot2u(v0.x, h4.x, a00);
      a01 = fdot2u(v0.y, h4.y, a01);
      a00 = fdot2u(v0.z, h4.z, a00);
      a01 = fdot2u(v0.w, h4.w, a01);
      uint4 v1 = wlds[(1 * 4 + c) * 512 + tid];
      a10 = fdot2u(v1.x, h4.x, a10);
      a11 = fdot2u(v1.y, h4.y, a11);
      a10 = fdot2u(v1.z, h4.z, a10);
      a11 = fdot2u(v1.w, h4.w, a11);
      uint4 v2 = wlds[(2 * 4 + c) * 512 + tid];
      a20 = fdot2u(v2.x, h4.x, a20);
      a21 = fdot2u(v2.y, h4.y, a21);
      a20 = fdot2u(v2.z, h4.z, a20);
      a21 = fdot2u(v2.w, h4.w, a21);
      uint4 v3 = wlds[(3 * 4 + c) * 512 + tid];
      a30 = fdot2u(v3.x, h4.x, a30);
      a31 = fdot2u(v3.y, h4.y, a31);
      a30 = fdot2u(v3.z, h4.z, a30);
      a31 = fdot2u(v3.w, h4.w, a31);
    }
    // fold this thread's xg rows into the matching gate partials, then
    // cross-pair reduce (partner holds the other K-half)
    float p0 = a00 + a01 + (odd ? 0.f : xga);   // gate i  (row j)
    float p1 = a10 + a11 + (odd ? 0.f : xgb);   // gate f  (row j+256)
    float p2 = a20 + a21 + (odd ? xga : 0.f);   // gate g  (row j+512)
    float p3 = a30 + a31 + (odd ? xgb : 0.f);   // gate o  (row j+768)
    float s0 = p0 + __shfl_xor(p0, 1);
    float s1 = p1 + __shfl_xor(p1, 1);
    float s2 = p2 + __shfl_xor(p2, 1);
    float s3 = p3 + __shfl_xor(p3, 1);

    c_ = sigmoidf_(s1) * c_ + sigmoidf_(s0) * tanhf_(s2);
    float h = sigmoidf_(s3) * tanhf_(c_);
    if (!odd) {
      stg_f32(hseq + t * 256 + j, h);  // device-coherent store
      union { _Float16 hf; uint16_t u; } cv;
      cv.hf = (_Float16)h;
      hbuf[pp ^ 1][j + ((j >> 7) << 3)] = cv.u;  // +8 elem skew for j>=128
    }
    __syncthreads();  // vmcnt(0) drain + hbuf visible
    if (tid == 0) cnt_store(&cnt[l * CNT_STRIDE], t + 1);
    pp ^= 1;
    xga = nxa;
    xgb = nxb;
  }
}

// proj: 512 thr, WG owns rows [half*512, half*512+512), 1 row/thread.
// 4-step chunks: one poll + one batched h-load RTT + one store-drain RTT
// amortize over 4 steps.
__device__ void proj_fn(int l, int half, const uint32_t* __restrict__ wpk,
                        const float* __restrict__ bih, const float* __restrict__ bhh,
                        const float* __restrict__ hsrc,   // hseq layer l-1 (f32)
                        float* __restrict__ xgdst, int* __restrict__ cnt) {
  __shared__ __align__(16) uint32_t hpk[4][128];  // 4 steps of packed fp16 h
  const int tid = threadIdx.x;
  const int row = half * 512 + tid;

  uint32_t wr_[128];
  {
    const uint4* g = reinterpret_cast<const uint4*>(wpk + (size_t)row * 128);
#pragma unroll
    for (int q = 0; q < 32; ++q) {
      uint4 v = g[q];
      wr_[4 * q + 0] = v.x; wr_[4 * q + 1] = v.y; wr_[4 * q + 2] = v.z; wr_[4 * q + 3] = v.w;
    }
  }
  const float bias = bih[row] + bhh[row];
  const int* prev = &cnt[(l - 1) * CNT_STRIDE];
  int* mine = &cnt[(4 + (l - 1) * 2 + half) * CNT_STRIDE];
  int rdy = 0;
  const int s4 = tid >> 7;    // pack slot 0..3 (step within chunk)
  const int c4 = tid & 127;   // column pair

  for (int tt = 0; tt < 128; ++tt) {
    const int t0 = tt * 4;
    wait_ge(prev, t0 + 4, rdy);  // h(t0..t0+3) visible
    {
      uint64_t hv = ldg_u64(hsrc + (t0 + s4) * 256 + 2 * c4);  // one RTT, batched
      float hx = __builtin_bit_cast(float, (uint32_t)hv);
      float hy = __builtin_bit_cast(float, (uint32_t)(hv >> 32));
      union { _Float16 h; uint16_t u; } a, b;
      a.h = (_Float16)hx;
      b.h = (_Float16)hy;
      hpk[s4][c4] = (uint32_t)a.u | ((uint32_t)b.u << 16);
    }
    __syncthreads();  // 4 steps of h staged
#pragma unroll
    for (int s = 0; s < 4; ++s) {
      float a0 = bias, a1 = 0.f;
      const uint4* hv4 = reinterpret_cast<const uint4*>(hpk[s]);
#pragma unroll
      for (int q = 0; q < 32; ++q) {
        uint4 h4 = hv4[q];
        a0 = fdot2u(wr_[4 * q + 0], h4.x, a0);
        a1 = fdot2u(wr_[4 * q + 1], h4.y, a1);
        a0 = fdot2u(wr_[4 * q + 2], h4.z, a0);
        a1 = fdot2u(wr_[4 * q + 3], h4.w, a1);
      }
      stg_f32(xgdst + (t0 + s) * 1024 + row, a0 + a1);
    }
    __syncthreads();  // all 4 xg stores drained; hpk reads done
    if (tid == 0) cnt_store(mine, t0 + 4);  // xg(0..t0+3) ready
  }
}

// final linear, fused: streams cnt[3]. 2 threads/row, f32 weights in regs.
// hs odd k-half at +16B bank skew (element 132) -> conflict-free reads.
__device__ void final_fn(const float* __restrict__ lrw, const float* __restrict__ lrb,
                         const float* __restrict__ h3, float* __restrict__ out,
                         const int* __restrict__ cnt) {
  __shared__ __align__(16) float hs[260];  // odd half at elem 132
  const int tid = threadIdx.x;
  const int row = tid >> 1;   // 0..255
  const int kh = tid & 1;     // k-half
  float w_[128];
  {
    const float4* g = reinterpret_cast<const float4*>(lrw + (size_t)row * 256 + kh * 128);
#pragma unroll
    for (int q = 0; q < 32; ++q) {
      float4 v = g[q];
      w_[4 * q + 0] = v.x; w_[4 * q + 1] = v.y; w_[4 * q + 2] = v.z; w_[4 * q + 3] = v.w;
    }
  }
  const float bias = lrb[row];
  const int* prev = &cnt[3 * CNT_STRIDE];
  int rdy = 0;
  for (int t = 0; t < 512; ++t) {
    wait_ge(prev, t + 1, rdy);
    if (tid < 128) {
      uint64_t hv = ldg_u64(h3 + t * 256 + 2 * tid);  // device-coherent 8B
      float2 f;
      f.x = __builtin_bit_cast(float, (uint32_t)hv);
      f.y = __builtin_bit_cast(float, (uint32_t)(hv >> 32));
      // cols (2tid, 2tid+1); both in same k-half; skew odd half by +4 elems
      *reinterpret_cast<float2*>(&hs[2 * tid + ((tid >> 6) << 2)]) = f;
    }
    __syncthreads();
    float a0 = 0.f, a1 = 0.f;
    const float* hp = hs + kh * 132;
#pragma unroll
    for (int k = 0; k < 128; k += 4) {
      a0 += w_[k] * hp[k] + w_[k + 2] * hp[k + 2];
      a1 += w_[k + 1] * hp[k + 1] + w_[k + 3] * hp[k + 3];
    }
    float s = a0 + a1;
    s += __shfl_xor(s, 1);  // combine k-halves
    if (!kh) out[t * 256 + row] = s + bias;  // plain store, d_out
    __syncthreads();  // hs reads done before next overwrite
  }
}

// grid.x = 11:
// 0=scan0 | 1,2=proj1 | 3=scan1 | 4,5=proj2 | 6=scan2 | 7,8=proj3 | 9=scan3 | 10=final
__global__ __launch_bounds__(512, 2) void pipeline(
    const uint32_t* __restrict__ wpkhh, const uint32_t* __restrict__ wpkih,
    const float* __restrict__ xg0, float* __restrict__ xgp,
    float* __restrict__ hseq,
    const float* __restrict__ bih1, const float* __restrict__ bhh1,
    const float* __restrict__ bih2, const float* __restrict__ bhh2,
    const float* __restrict__ bih3, const float* __restrict__ bhh3,
    const float* __restrict__ lrw, const float* __restrict__ lrb,
    float* __restrict__ out, int* __restrict__ cnt) {
  const int bx = blockIdx.x;
  if (bx == 0) {
    scan_fn(0, wpkhh, xg0, hseq, cnt);
  } else if (bx == 10) {
    final_fn(lrw, lrb, hseq + (size_t)3 * 131072, out, cnt);
  } else {
    const int g = bx - 1;
    const int l = g / 3 + 1;
    const int r = g % 3;
    const float* bih = (l == 1) ? bih1 : (l == 2) ? bih2 : bih3;
    const float* bhh = (l == 1) ? bhh1 : (l == 2) ? bhh2 : bhh3;
    if (r < 2)
      proj_fn(l, r, wpkih + (size_t)(l - 1) * 131072, bih, bhh,
              hseq + (size_t)(l - 1) * 131072, xgp + (size_t)(l - 1) * 524288, cnt);
    else
      scan_fn(l, wpkhh + (size_t)l * 131072, xgp + (size_t)(l - 1) * 524288,
              hseq + (size_t)l * 131072, cnt);
  }
}

extern "C" void kernel_launch(void* const* d_in, const int* in_sizes, int n_in,
                              void* d_out, int out_size, void* d_ws, size_t ws_size,
                              hipStream_t stream) {
  (void)in_sizes; (void)n_in; (void)out_size; (void)ws_size;
  const float* x = (const float*)d_in[0];
  const float* wih[4] = {(const float*)d_in[1], (const float*)d_in[5],
                         (const float*)d_in[9], (const float*)d_in[13]};
  const float* whh[4] = {(const float*)d_in[2], (const float*)d_in[6],
                         (const float*)d_in[10], (const float*)d_in[14]};
  const float* bih[4] = {(const float*)d_in[3], (const float*)d_in[7],
                         (const float*)d_in[11], (const float*)d_in[15]};
  const float* bhh[4] = {(const float*)d_in[4], (const float*)d_in[8],
                         (const float*)d_in[12], (const float*)d_in[16]};
  const float* lrw = (const float*)d_in[17];
  const float* lrb = (const float*)d_in[18];
  float* out = (float*)d_out;

  // ws layout (4B units):
  //   xg0[524288] | xgp[3*524288] | hseq[4*131072] | wpkhh u32[4*131072]
  //   | wpkih u32[3*131072] | cnt int[16*CNT_STRIDE]      (~14.2 MB total)
  float* ws = (float*)d_ws;
  float* xg0 = ws;
  float* xgp = ws + 524288;
  float* hseq = xgp + 3 * 524288;
  uint32_t* wpkhh = (uint32_t*)(hseq + 4 * 131072);
  uint32_t* wpkih = wpkhh + 4 * 131072;
  int* cnt = (int*)(wpkih + 3 * 131072);

  // one dispatch packs whh[0..3] then wih[1..3] into the contiguous region
  pack_all<<<3584, 256, 0, stream>>>(whh[0], whh[1], whh[2], whh[3],
                                     wih[1], wih[2], wih[3], wpkhh);

  // layer-0 projection from x (batch element 255); block (0,0) zeroes cnt
  proj_gemm<<<dim3(4, 64), 256, 0, stream>>>(x + 255 * 512, 256 * 512, 512,
                                             wih[0], bih[0], bhh[0], xg0, cnt);

  pipeline<<<11, 512, 0, stream>>>(wpkhh, wpkih, xg0, xgp, hseq,
                                   bih[1], bhh[1], bih[2], bhh[2], bih[3], bhh[3],
                                   lrw, lrb, out, cnt);
}